// Round 5
// baseline (368.941 us; speedup 1.0000x reference)
//
#include <hip/hip_runtime.h>
#include <math.h>

#define TILE 256
#define PPT  8   // points per thread

__device__ __forceinline__ float fast_rcp(float x) { return __builtin_amdgcn_rcpf(x); }
__device__ __forceinline__ float fast_rsq(float x) { return __builtin_amdgcn_rsqf(x); }

// atan(t) for |t| <~ 0.3 (near-straight chain). Truncation < 2e-9 at |t|=0.2.
__device__ __forceinline__ float atan_poly(float t) {
    const float c3 = -0.3333333333f, c5 = 0.2f, c7 = -0.1428571429f, c9 = 0.1111111111f;
    float t2 = t * t;
    return t * fmaf(t2, fmaf(t2, fmaf(t2, fmaf(t2, c9, c7), c5), c3), 1.0f);
}

// Thread t owns points p0..p0+7 (p0 = 8t). Computes hinges p0-2..p0+7 (10) and
// edges p0-1..p0+7 (9), accumulating straight into 8 force registers — no
// g/s arrays, no LDS, no barriers until the final energy reduction.
__global__ __launch_bounds__(TILE) void hinge_chain_kernel(
    const float2* __restrict__ pos,         // N points
    const float*  __restrict__ thetas_ss,   // H = N-2
    const float*  __restrict__ rest_len,    // E = N-1
    const float*  __restrict__ k_stiff_p,
    const float*  __restrict__ k_soft_p,
    const float*  __restrict__ k_stretch_p,
    const int2*   __restrict__ buckle,      // H x 2
    float*        __restrict__ out,         // 3 + 2N
    float2*       __restrict__ partials,    // one (rot,str) per block
    int N)
{
    const int H = N - 2;
    const int E = N - 1;
    const int gid = blockIdx.x * TILE + threadIdx.x;
    const int p0  = gid * PPT;

    const float k_stiff   = *k_stiff_p;
    const float k_soft    = *k_soft_p;
    const float k_stretch = *k_stretch_p;

    float2 P[12];       // pos[p0-2 .. p0+9]
    float  tss[10];     // thetas_ss[p0-2 .. p0+7]
    int2   bb[10];      // buckle   [p0-2 .. p0+7]
    float  rl[9];       // rest_len [p0-1 .. p0+7]

    const bool interior = (p0 >= 2) && (p0 + 9 < N);
    if (interior) {
        // p0 = 8t: all vector loads naturally aligned (pos/buckle 16B, theta 8B).
        const float4* p4 = reinterpret_cast<const float4*>(pos + (p0 - 2));
        #pragma unroll
        for (int i = 0; i < 6; ++i) {
            float4 v = p4[i];
            P[2 * i]     = make_float2(v.x, v.y);
            P[2 * i + 1] = make_float2(v.z, v.w);
        }
        float2 t01 = *reinterpret_cast<const float2*>(thetas_ss + (p0 - 2));
        float4 t25 = *reinterpret_cast<const float4*>(thetas_ss + p0);
        float4 t69 = *reinterpret_cast<const float4*>(thetas_ss + p0 + 4);
        tss[0] = t01.x; tss[1] = t01.y;
        tss[2] = t25.x; tss[3] = t25.y; tss[4] = t25.z; tss[5] = t25.w;
        tss[6] = t69.x; tss[7] = t69.y; tss[8] = t69.z; tss[9] = t69.w;
        rl[0] = rest_len[p0 - 1];
        float4 r14 = *reinterpret_cast<const float4*>(rest_len + p0);
        float4 r58 = *reinterpret_cast<const float4*>(rest_len + p0 + 4);
        rl[1] = r14.x; rl[2] = r14.y; rl[3] = r14.z; rl[4] = r14.w;
        rl[5] = r58.x; rl[6] = r58.y; rl[7] = r58.z; rl[8] = r58.w;
        const int4* b4 = reinterpret_cast<const int4*>(buckle + (p0 - 2));
        #pragma unroll
        for (int i = 0; i < 5; ++i) {
            int4 u = b4[i];
            bb[2 * i]     = make_int2(u.x, u.y);
            bb[2 * i + 1] = make_int2(u.z, u.w);
        }
    } else {
        #pragma unroll
        for (int j = 0; j < 12; ++j) {
            int p = p0 - 2 + j;
            P[j] = (p >= 0 && p < N) ? pos[p] : make_float2(0.f, 0.f);
        }
        #pragma unroll
        for (int j = 0; j < 10; ++j) {
            int h = p0 - 2 + j;
            bool v = (h >= 0 && h < H);
            tss[j] = v ? thetas_ss[h] : 0.f;
            bb[j]  = v ? buckle[h]    : make_int2(0, 0);
        }
        #pragma unroll
        for (int k = 0; k < 9; ++k) {
            int e = p0 - 1 + k;
            rl[k] = (e >= 0 && e < E) ? rest_len[e] : 1.f;
        }
    }

    float gx[PPT], gy[PPT];
    #pragma unroll
    for (int m = 0; m < PPT; ++m) { gx[m] = 0.f; gy[m] = 0.f; }
    float rot_e = 0.f, str_e = 0.f;

    // ---- 10 hinges, folded straight into force accumulators ----
    #pragma unroll
    for (int j = 0; j < 10; ++j) {
        int h = p0 - 2 + j;
        bool hvalid = (h >= 0) && (h < H);
        if (hvalid) {
            float2 a = P[j], b = P[j + 1], c = P[j + 2];
            float v1x = b.x - a.x, v1y = b.y - a.y;
            float v2x = c.x - b.x, v2y = c.y - b.y;
            float cr = v1x * v2y - v1y * v2x;
            float dt = v1x * v2x + v1y * v2y;
            // near-straight chain: dot > 0 always
            float th = atan_poly(cr * fast_rcp(dt));
            float ts = tss[j];
            int2  bk = bb[j];
            float dth = th - ts;
            bool m0 = (bk.x == 1 && th > -ts) || (bk.x == -1 && th < ts);
            bool m1 = (bk.y == 1 && th > -ts) || (bk.y == -1 && th < ts);
            float K = (m0 ? k_stiff : k_soft) + (m1 ? k_stiff : k_soft);
            if (j >= 2) rot_e += 0.5f * K * dth * dth;   // own hinges only
            float inv = (K * dth) * fast_rcp(cr * cr + dt * dt);
            float g1x = inv * ( dt * v2y - cr * v2x);
            float g1y = inv * (-dt * v2x - cr * v2y);
            float g2x = inv * (-dt * v1y - cr * v1x);
            float g2y = inv * ( dt * v1x - cr * v1y);
            // point A = h (m=j-2): grad -= g1 ; B = h+1 (m=j-1): grad += g1-g2 ;
            // point C = h+2 (m=j): grad += g2
            if (j >= 2)           { gx[j - 2] -= g1x;       gy[j - 2] -= g1y; }
            if (j >= 1 && j <= 8) { gx[j - 1] += g1x - g2x; gy[j - 1] += g1y - g2y; }
            if (j <= 7)           { gx[j]     += g2x;       gy[j]     += g2y; }
        }
    }

    // ---- 9 edges, folded straight into force accumulators ----
    #pragma unroll
    for (int k = 0; k < 9; ++k) {
        int e = p0 - 1 + k;
        bool ev = (e >= 0) && (e < E);
        if (ev) {
            float2 a = P[k + 1], b = P[k + 2];
            float ex = b.x - a.x, ey = b.y - a.y;
            float d2   = ex * ex + ey * ey;
            float invl = fast_rsq(d2);
            float d    = d2 * invl - rl[k];
            if (k >= 1) str_e += 0.5f * k_stretch * d * d;   // own edges only
            float cc = k_stretch * d * invl;
            float sx = cc * ex, sy = cc * ey;
            // point e (m=k-1): grad -= s ; point e+1 (m=k): grad += s
            if (k >= 1) { gx[k - 1] -= sx; gy[k - 1] -= sy; }
            if (k <= 7) { gx[k]     += sx; gy[k]     += sy; }
        }
    }

    // ---- force stores (never re-read: nontemporal) ----
    #pragma unroll
    for (int m = 0; m < PPT; ++m) {
        int p = p0 + m;
        if (p < N) {
            float fx = -gx[m], fy = -gy[m];
            if (p < 2) { fx = 0.f; fy = 0.f; }   // first 4 coords fixed
            __builtin_nontemporal_store(fx, out + 3 + 2 * p);
            __builtin_nontemporal_store(fy, out + 4 + 2 * p);
        }
    }

    // ---- energy reduction: block partial -> ws ----
    for (int off = 32; off > 0; off >>= 1) {
        rot_e += __shfl_down(rot_e, off);
        str_e += __shfl_down(str_e, off);
    }
    __shared__ float wr[TILE / 64], wsum[TILE / 64];
    int wave = threadIdx.x >> 6, lane = threadIdx.x & 63;
    if (lane == 0) { wr[wave] = rot_e; wsum[wave] = str_e; }
    __syncthreads();
    if (threadIdx.x == 0) {
        float r = 0.f, ss = 0.f;
        for (int w = 0; w < TILE / 64; ++w) { r += wr[w]; ss += wsum[w]; }
        partials[blockIdx.x] = make_float2(r, ss);
    }
}

__global__ __launch_bounds__(256) void reduce_partials_kernel(
    const float2* __restrict__ partials, int nblocks,
    float* __restrict__ out)
{
    const int tid = threadIdx.x;
    float r0 = 0.f, s0 = 0.f, r1 = 0.f, s1 = 0.f;
    int i = tid;
    for (; i + 256 < nblocks; i += 512) {
        float2 a = partials[i];
        float2 b = partials[i + 256];
        r0 += a.x; s0 += a.y;
        r1 += b.x; s1 += b.y;
    }
    if (i < nblocks) { float2 a = partials[i]; r0 += a.x; s0 += a.y; }
    float r = r0 + r1, s = s0 + s1;
    for (int off = 32; off > 0; off >>= 1) {
        r += __shfl_down(r, off);
        s += __shfl_down(s, off);
    }
    __shared__ float wr[4], wsv[4];
    int wave = tid >> 6, lane = tid & 63;
    if (lane == 0) { wr[wave] = r; wsv[wave] = s; }
    __syncthreads();
    if (tid == 0) {
        float R = 0.f, S = 0.f;
        for (int w = 0; w < 4; ++w) { R += wr[w]; S += wsv[w]; }
        out[0] = R + S;
        out[1] = R;
        out[2] = S;
    }
}

extern "C" void kernel_launch(void* const* d_in, const int* in_sizes, int n_in,
                              void* d_out, int out_size, void* d_ws, size_t ws_size,
                              hipStream_t stream) {
    const float2* pos       = (const float2*)d_in[0];
    const float*  thetas_ss = (const float*)d_in[1];
    const float*  rest_len  = (const float*)d_in[2];
    const float*  k_stiff   = (const float*)d_in[3];
    const float*  k_soft    = (const float*)d_in[4];
    const float*  k_stretch = (const float*)d_in[5];
    const int2*   buckle    = (const int2*)d_in[6];
    float*        out       = (float*)d_out;
    float2*       partials  = (float2*)d_ws;

    const int N = in_sizes[0] / 2;                       // points
    const int nthreads = (N + PPT - 1) / PPT;
    const int grid = (nthreads + TILE - 1) / TILE;

    hinge_chain_kernel<<<grid, TILE, 0, stream>>>(
        pos, thetas_ss, rest_len, k_stiff, k_soft, k_stretch, buckle, out, partials, N);

    reduce_partials_kernel<<<1, 256, 0, stream>>>(partials, grid, out);
}

// Round 6
// 224.130 us; speedup vs baseline: 1.6461x; 1.6461x over previous
//
#include <hip/hip_runtime.h>
#include <math.h>

#define TILE 256
#define PPT  8                 // points per thread
#define BPTS (TILE * PPT)      // 2048 points per block
#define BDW  (2 * BPTS)        // 4096 force dwords per block

__device__ __forceinline__ float fast_rcp(float x) { return __builtin_amdgcn_rcpf(x); }
__device__ __forceinline__ float fast_rsq(float x) { return __builtin_amdgcn_rsqf(x); }

// atan(t) for |t| <~ 0.3 (near-straight chain). Truncation < 2e-9 at |t|=0.2.
__device__ __forceinline__ float atan_poly(float t) {
    const float c3 = -0.3333333333f, c5 = 0.2f, c7 = -0.1428571429f, c9 = 0.1111111111f;
    float t2 = t * t;
    return t * fmaf(t2, fmaf(t2, fmaf(t2, fmaf(t2, c9, c7), c5), c3), 1.0f);
}

// Thread t owns points p0..p0+7 (p0 = 8t): computes hinges p0-2..p0+7 (10) and
// edges p0-1..p0+7 (9) in registers, folds into 8 force accumulators, stages
// forces in LDS (pad 17 dwords/thread), then the block emits coalesced aligned
// float4 stores (1-dword head + 1023 float4 + 3-dword tail handles the +3 offset).
__global__ __launch_bounds__(TILE) void hinge_chain_kernel(
    const float2* __restrict__ pos,         // N points
    const float*  __restrict__ thetas_ss,   // H = N-2
    const float*  __restrict__ rest_len,    // E = N-1
    const float*  __restrict__ k_stiff_p,
    const float*  __restrict__ k_soft_p,
    const float*  __restrict__ k_stretch_p,
    const int2*   __restrict__ buckle,      // H x 2
    float*        __restrict__ out,         // 3 + 2N
    float2*       __restrict__ partials,    // one (rot,str) per block
    int N, int out_dwords)
{
    const int H = N - 2;
    const int E = N - 1;
    const int gid = blockIdx.x * TILE + threadIdx.x;
    const int p0  = gid * PPT;

    const float k_stiff   = *k_stiff_p;
    const float k_soft    = *k_soft_p;
    const float k_stretch = *k_stretch_p;

    float2 P[12];       // pos[p0-2 .. p0+9]
    float  tss[10];     // thetas_ss[p0-2 .. p0+7]
    int2   bb[10];      // buckle   [p0-2 .. p0+7]
    float  rl[9];       // rest_len [p0-1 .. p0+7]

    const bool interior = (p0 >= 2) && (p0 + 9 < N);
    if (interior) {
        const float4* p4 = reinterpret_cast<const float4*>(pos + (p0 - 2));
        #pragma unroll
        for (int i = 0; i < 6; ++i) {
            float4 v = p4[i];
            P[2 * i]     = make_float2(v.x, v.y);
            P[2 * i + 1] = make_float2(v.z, v.w);
        }
        float2 t01 = *reinterpret_cast<const float2*>(thetas_ss + (p0 - 2));
        float4 t25 = *reinterpret_cast<const float4*>(thetas_ss + p0);
        float4 t69 = *reinterpret_cast<const float4*>(thetas_ss + p0 + 4);
        tss[0] = t01.x; tss[1] = t01.y;
        tss[2] = t25.x; tss[3] = t25.y; tss[4] = t25.z; tss[5] = t25.w;
        tss[6] = t69.x; tss[7] = t69.y; tss[8] = t69.z; tss[9] = t69.w;
        rl[0] = rest_len[p0 - 1];
        float4 r14 = *reinterpret_cast<const float4*>(rest_len + p0);
        float4 r58 = *reinterpret_cast<const float4*>(rest_len + p0 + 4);
        rl[1] = r14.x; rl[2] = r14.y; rl[3] = r14.z; rl[4] = r14.w;
        rl[5] = r58.x; rl[6] = r58.y; rl[7] = r58.z; rl[8] = r58.w;
        const int4* b4 = reinterpret_cast<const int4*>(buckle + (p0 - 2));
        #pragma unroll
        for (int i = 0; i < 5; ++i) {
            int4 u = b4[i];
            bb[2 * i]     = make_int2(u.x, u.y);
            bb[2 * i + 1] = make_int2(u.z, u.w);
        }
    } else {
        #pragma unroll
        for (int j = 0; j < 12; ++j) {
            int p = p0 - 2 + j;
            P[j] = (p >= 0 && p < N) ? pos[p] : make_float2(0.f, 0.f);
        }
        #pragma unroll
        for (int j = 0; j < 10; ++j) {
            int h = p0 - 2 + j;
            bool v = (h >= 0 && h < H);
            tss[j] = v ? thetas_ss[h] : 0.f;
            bb[j]  = v ? buckle[h]    : make_int2(0, 0);
        }
        #pragma unroll
        for (int k = 0; k < 9; ++k) {
            int e = p0 - 1 + k;
            rl[k] = (e >= 0 && e < E) ? rest_len[e] : 1.f;
        }
    }

    float gx[PPT], gy[PPT];
    #pragma unroll
    for (int m = 0; m < PPT; ++m) { gx[m] = 0.f; gy[m] = 0.f; }
    float rot_e = 0.f, str_e = 0.f;

    // ---- 10 hinges, folded straight into force accumulators ----
    #pragma unroll
    for (int j = 0; j < 10; ++j) {
        int h = p0 - 2 + j;
        bool hvalid = (h >= 0) && (h < H);
        if (hvalid) {
            float2 a = P[j], b = P[j + 1], c = P[j + 2];
            float v1x = b.x - a.x, v1y = b.y - a.y;
            float v2x = c.x - b.x, v2y = c.y - b.y;
            float cr = v1x * v2y - v1y * v2x;
            float dt = v1x * v2x + v1y * v2y;
            float th = atan_poly(cr * fast_rcp(dt));   // dot > 0 structurally
            float ts = tss[j];
            int2  bk = bb[j];
            float dth = th - ts;
            bool m0 = (bk.x == 1 && th > -ts) || (bk.x == -1 && th < ts);
            bool m1 = (bk.y == 1 && th > -ts) || (bk.y == -1 && th < ts);
            float K = (m0 ? k_stiff : k_soft) + (m1 ? k_stiff : k_soft);
            if (j >= 2) rot_e += 0.5f * K * dth * dth;   // own hinges only
            float inv = (K * dth) * fast_rcp(cr * cr + dt * dt);
            float g1x = inv * ( dt * v2y - cr * v2x);
            float g1y = inv * (-dt * v2x - cr * v2y);
            float g2x = inv * (-dt * v1y - cr * v1x);
            float g2y = inv * ( dt * v1x - cr * v1y);
            if (j >= 2)           { gx[j - 2] -= g1x;       gy[j - 2] -= g1y; }
            if (j >= 1 && j <= 8) { gx[j - 1] += g1x - g2x; gy[j - 1] += g1y - g2y; }
            if (j <= 7)           { gx[j]     += g2x;       gy[j]     += g2y; }
        }
    }

    // ---- 9 edges, folded straight into force accumulators ----
    #pragma unroll
    for (int k = 0; k < 9; ++k) {
        int e = p0 - 1 + k;
        bool ev = (e >= 0) && (e < E);
        if (ev) {
            float2 a = P[k + 1], b = P[k + 2];
            float ex = b.x - a.x, ey = b.y - a.y;
            float d2   = ex * ex + ey * ey;
            float invl = fast_rsq(d2);
            float d    = d2 * invl - rl[k];
            if (k >= 1) str_e += 0.5f * k_stretch * d * d;   // own edges only
            float cc = k_stretch * d * invl;
            float sx = cc * ex, sy = cc * ey;
            if (k >= 1) { gx[k - 1] -= sx; gy[k - 1] -= sy; }
            if (k <= 7) { gx[k]     += sx; gy[k]     += sy; }
        }
    }

    // ---- stage forces to LDS (pad 17 dwords/thread -> conflict-free) ----
    __shared__ float lf[TILE * 17];
    #pragma unroll
    for (int m = 0; m < PPT; ++m) {
        int p = p0 + m;
        float fx = -gx[m], fy = -gy[m];
        if (p < 2 || p >= N) { fx = 0.f; fy = 0.f; }
        lf[17 * threadIdx.x + 2 * m]     = fx;
        lf[17 * threadIdx.x + 2 * m + 1] = fy;
    }
    __syncthreads();

    // ---- coalesced block store: local dword d lives at lf[d + (d>>4)] ----
    const long long base3 = 3LL + (long long)blockIdx.x * BDW;
    if (base3 + BDW <= (long long)out_dwords) {
        // head (1 dword) + 1023 aligned float4 + tail (3 dwords)
        #pragma unroll
        for (int r = 0; r < 4; ++r) {
            int f = threadIdx.x + TILE * r;
            if (f < 1023) {
                int d0 = 1 + 4 * f;
                float4 v;
                v.x = lf[d0     + ((d0    ) >> 4)];
                v.y = lf[d0 + 1 + ((d0 + 1) >> 4)];
                v.z = lf[d0 + 2 + ((d0 + 2) >> 4)];
                v.w = lf[d0 + 3 + ((d0 + 3) >> 4)];
                *reinterpret_cast<float4*>(out + base3 + 1 + 4 * f) = v;
            }
        }
        if (threadIdx.x == 0) {
            out[base3] = lf[0];
            #pragma unroll
            for (int d = BDW - 3; d < BDW; ++d)
                out[base3 + d] = lf[d + (d >> 4)];
        }
    } else {
        // edge block: bounds-checked coalesced dword stores
        for (int i = 0; i < 2 * PPT; ++i) {
            int d = threadIdx.x + TILE * i;
            long long g = base3 + d;
            if (g < (long long)out_dwords) out[g] = lf[d + (d >> 4)];
        }
    }

    // ---- energy reduction: block partial -> ws ----
    for (int off = 32; off > 0; off >>= 1) {
        rot_e += __shfl_down(rot_e, off);
        str_e += __shfl_down(str_e, off);
    }
    __shared__ float wr[TILE / 64], wsum[TILE / 64];
    int wave = threadIdx.x >> 6, lane = threadIdx.x & 63;
    if (lane == 0) { wr[wave] = rot_e; wsum[wave] = str_e; }
    __syncthreads();
    if (threadIdx.x == 0) {
        float r = 0.f, ss = 0.f;
        for (int w = 0; w < TILE / 64; ++w) { r += wr[w]; ss += wsum[w]; }
        partials[blockIdx.x] = make_float2(r, ss);
    }
}

__global__ __launch_bounds__(256) void reduce_partials_kernel(
    const float2* __restrict__ partials, int nblocks,
    float* __restrict__ out)
{
    const int tid = threadIdx.x;
    float r0 = 0.f, s0 = 0.f, r1 = 0.f, s1 = 0.f;
    int i = tid;
    for (; i + 256 < nblocks; i += 512) {
        float2 a = partials[i];
        float2 b = partials[i + 256];
        r0 += a.x; s0 += a.y;
        r1 += b.x; s1 += b.y;
    }
    if (i < nblocks) { float2 a = partials[i]; r0 += a.x; s0 += a.y; }
    float r = r0 + r1, s = s0 + s1;
    for (int off = 32; off > 0; off >>= 1) {
        r += __shfl_down(r, off);
        s += __shfl_down(s, off);
    }
    __shared__ float wr[4], wsv[4];
    int wave = tid >> 6, lane = tid & 63;
    if (lane == 0) { wr[wave] = r; wsv[wave] = s; }
    __syncthreads();
    if (tid == 0) {
        float R = 0.f, S = 0.f;
        for (int w = 0; w < 4; ++w) { R += wr[w]; S += wsv[w]; }
        out[0] = R + S;
        out[1] = R;
        out[2] = S;
    }
}

extern "C" void kernel_launch(void* const* d_in, const int* in_sizes, int n_in,
                              void* d_out, int out_size, void* d_ws, size_t ws_size,
                              hipStream_t stream) {
    const float2* pos       = (const float2*)d_in[0];
    const float*  thetas_ss = (const float*)d_in[1];
    const float*  rest_len  = (const float*)d_in[2];
    const float*  k_stiff   = (const float*)d_in[3];
    const float*  k_soft    = (const float*)d_in[4];
    const float*  k_stretch = (const float*)d_in[5];
    const int2*   buckle    = (const int2*)d_in[6];
    float*        out       = (float*)d_out;
    float2*       partials  = (float2*)d_ws;

    const int N = in_sizes[0] / 2;                       // points
    const int grid = (N + BPTS - 1) / BPTS;

    hinge_chain_kernel<<<grid, TILE, 0, stream>>>(
        pos, thetas_ss, rest_len, k_stiff, k_soft, k_stretch, buckle, out, partials,
        N, out_size);

    reduce_partials_kernel<<<1, 256, 0, stream>>>(partials, grid, out);
}